// Round 15
// baseline (183.272 us; speedup 1.0000x reference)
//
#include <hip/hip_runtime.h>
#include <stdint.h>

// Problem constants: B=2, S=2048, H=1024, NH=16, HD=64, K=1024
// Inputs FP32 -> one cvt pass to bf16 -> bf16 MFMA pipeline -> output FP32.

typedef __attribute__((ext_vector_type(8))) short short8;
typedef __attribute__((ext_vector_type(4))) float floatx4;
typedef __attribute__((ext_vector_type(4))) unsigned int uint4v;
typedef __attribute__((ext_vector_type(2))) unsigned int uint2v;

__device__ __forceinline__ unsigned short f2bf(float f) {          // RNE
    unsigned int u = __float_as_uint(f);
    unsigned int r = u + 0x7fffu + ((u >> 16) & 1u);
    return (unsigned short)(r >> 16);
}
// pack two fp32 -> bf16x2 dword
#if __has_builtin(__builtin_amdgcn_cvt_pk_bf16_f32)
__device__ __forceinline__ unsigned int pack_bf2(float lo, float hi) {
    auto v = __builtin_amdgcn_cvt_pk_bf16_f32(lo, hi);
    return __builtin_bit_cast(unsigned int, v);
}
#else
__device__ __forceinline__ unsigned int pack_bf2(float lo, float hi) {
    unsigned int a = __float_as_uint(lo) + 0x8000u;
    unsigned int b = __float_as_uint(hi) + 0x8000u;
    return __builtin_amdgcn_perm(b, a, 0x07060302u);
}
#endif

// raw exp2 (v_exp_f32) when available
#if __has_builtin(__builtin_amdgcn_exp2f)
#define EXP2(x) __builtin_amdgcn_exp2f(x)
#else
#define EXP2(x) exp2f(x)
#endif

// async global->LDS, 16B per lane. LDS dest: wave-uniform base + lane*16.
__device__ __forceinline__ void gl2lds16(const void* g, void* l) {
    __builtin_amdgcn_global_load_lds(
        (const __attribute__((address_space(1))) unsigned int*)g,
        (__attribute__((address_space(3))) unsigned int*)l, 16, 0, 0);
}

#define MFMA32(a, b, c) __builtin_amdgcn_mfma_f32_16x16x32_bf16((a), (b), (c), 0, 0, 0)

// ---------------------------------------------------------------------------
// One-pass prep: fp32->bf16 for hidden / w_qkv / w_out, plus mask transform
// m2 = mask*log2(e) - 10*log2(e) (fp32). Grid exactly 8196 x 256.
// ---------------------------------------------------------------------------
__global__ __launch_bounds__(256)
void cvt_all(const float* __restrict__ a, const float* __restrict__ b,
             const float* __restrict__ c, const float* __restrict__ mask,
             unsigned short* __restrict__ oa, unsigned short* __restrict__ ob,
             unsigned short* __restrict__ oc, float* __restrict__ m2b)
{
    int i = blockIdx.x * 256 + threadIdx.x;
    if (i >= 2097152) {                     // mask range: 1024 groups
        int off = i - 2097152;
        float4 v = *(const float4*)(mask + (size_t)off * 4);
        const float L2E = 1.44269504f, C2 = -14.4269504f;
        float4 w;
        w.x = fmaf(v.x, L2E, C2); w.y = fmaf(v.y, L2E, C2);
        w.z = fmaf(v.z, L2E, C2); w.w = fmaf(v.w, L2E, C2);
        *(float4*)(m2b + (size_t)off * 4) = w;
        return;
    }
    const float* src; unsigned short* dst; int off;
    if (i < 1048576)      { src = a; dst = oa; off = i; }
    else if (i < 1835008) { src = b; dst = ob; off = i - 1048576; }
    else                  { src = c; dst = oc; off = i - 1835008; }
    float4 v = *(const float4*)(src + (size_t)off * 4);
    uint2v w;
    w[0] = pack_bf2(v.x, v.y);
    w[1] = pack_bf2(v.z, v.w);
    *(uint2v*)(dst + (size_t)off * 4) = w;
}

// ---------------------------------------------------------------------------
// NT GEMM v5 (verified round 14: gemm_nt left the top-5):
// WAVES-parametrized 128 x BN tile, BK=32, tri-buffered LDS + depth-2
// prefetch + counted vmcnt. MODE0 uses 8 waves (512 threads): per-wave
// slice acc[2][4], 48KB LDS -> 3 blocks/CU = 24 waves/CU = 6 waves/SIMD.
// MODE1 keeps the verified 4-wave path.
//   WAVES/2 row-groups x 2 col-groups; MI = 16/WAVES row sub-tiles;
//   NA = 8/WAVES, NB = BN/(16*WAVES) DMAs per wave per stage.
//   vmcnt ledger: steady 2*(NA+NB), tail NA+NB, then 0.
// LDS layout (verified 0-conflict): 128B paired-row lines (2 M-rows x 64B),
// 8x16B slots XOR-swizzled by (line&7). Stage side pre-swizzles the GLOBAL
// source address; LDS dest stays linear (gl2lds requirement).
// MODE 0: scatter bf16 to q/k ([B,NH,S,HD]) + V^T ([B,NH,HD,S'])
//         S' key-interleaved within 32-groups:
//         k' = (k&~31) | ((k>>2)&3)<<3 | ((k>>4)&1)<<2 | (k&3).
//         q PRE-SCALED by 0.125*log2(e) so attn exp2's the raw MFMA out.
// MODE 1: fp32 store outf[m*N+n].
// ---------------------------------------------------------------------------
template<int MODE, int BN, int WAVES>
__global__ __launch_bounds__(WAVES * 64)
void gemm_nt(const unsigned short* __restrict__ A,
             const unsigned short* __restrict__ Bm,
             unsigned short* __restrict__ out0,
             unsigned short* __restrict__ out1,
             unsigned short* __restrict__ out2,
             float* __restrict__ outf,
             int N)
{
    constexpr int BUFB  = 8192 + BN * 64;        // bytes per buffer (A + B)
    constexpr int NSTEP = 32;                    // K / 32
    constexpr int NA    = 8 / WAVES;             // A DMAs per wave per stage
    constexpr int NB    = BN / (16 * WAVES);     // B DMAs per wave per stage
    constexpr int BSL   = BN / 32;               // col sub-tiles per wave
    constexpr int MI    = 16 / WAVES;            // row sub-tiles per wave
    __shared__ unsigned char smem[3 * BUFB];
    const int K = 1024;
    const int tid  = threadIdx.x;
    const int wave = tid >> 6, lane = tid & 63;
    const int l15  = lane & 15, quad = lane >> 4;
    const int wm = wave >> 1, wn = wave & 1;

    int Lid = blockIdx.y * gridDim.x + blockIdx.x;
    int bm = (Lid & 7) * 4 + ((Lid >> 3) & 3);
    int bn = Lid >> 5;

    floatx4 acc[MI][BSL];
#pragma unroll
    for (int i = 0; i < MI; i++)
#pragma unroll
        for (int j = 0; j < BSL; j++)
            acc[i][j] = floatx4{0.f, 0.f, 0.f, 0.f};

    // staging maps: chunk s (16B units) -> LDS line L = s>>3, slot p = s&7.
    // content q = p ^ (L&7): global (Mrow = L*2 + (q>>2), Kblk = q&3).
    int soffA[NA], soffB[NB];
#pragma unroll
    for (int l = 0; l < NA; l++) {
        int s = (wave * NA + l) * 64 + lane;
        int L = s >> 3, q = (s & 7) ^ (L & 7);
        soffA[l] = (L * 2 + (q >> 2)) * K + (q & 3) * 8;
    }
#pragma unroll
    for (int l = 0; l < NB; l++) {
        int s = (wave * NB + l) * 64 + lane;
        int L = s >> 3, q = (s & 7) ^ (L & 7);
        soffB[l] = (L * 2 + (q >> 2)) * K + (q & 3) * 8;
    }
    // read maps: row r, K-block quad -> line r>>1, slot (((r&1)<<2)|quad)^(line&7)
    int aoff[MI], boff[BSL];
#pragma unroll
    for (int i = 0; i < MI; i++) {
        int r = wm * (MI * 16) + i * 16 + l15, L = r >> 1;
        aoff[i] = L * 128 + (((((r & 1) << 2) | quad) ^ (L & 7)) * 16);
    }
#pragma unroll
    for (int j = 0; j < BSL; j++) {
        int r = wn * (BN / 2) + j * 16 + l15, L = r >> 1;
        boff[j] = 8192 + L * 128 + (((((r & 1) << 2) | quad) ^ (L & 7)) * 16);
    }

    const unsigned short* Abase = A  + (size_t)(bm * 128) * K;
    const unsigned short* Bbase = Bm + (size_t)(bn * BN) * K;

    auto STAGE = [&](int u, int bufb) {
        const int k0 = u * 32;
#pragma unroll
        for (int l = 0; l < NA; l++)
            gl2lds16(Abase + (size_t)soffA[l] + k0, &smem[bufb + (wave * NA + l) * 1024]);
#pragma unroll
        for (int l = 0; l < NB; l++)
            gl2lds16(Bbase + (size_t)soffB[l] + k0, &smem[bufb + 8192 + (wave * NB + l) * 1024]);
    };

    // prologue: stages 0,1 into buffers 0,1
    STAGE(0, 0);
    STAGE(1, BUFB);

    int b0 = 0, b2 = 2;                          // compute buf, stage buf
    for (int t = 0; t < NSTEP; t++) {
        // barrier 1: all waves done computing step t-1 -> buf[b2] reusable
        asm volatile("" ::: "memory");
        __builtin_amdgcn_s_barrier();
        asm volatile("" ::: "memory");
        if (t + 2 < NSTEP) {
            STAGE(t + 2, b2 * BUFB);
            // retire stage(t); stages t+1,t+2 (2*(NA+NB)) stay in flight
            if (NA + NB == 2) asm volatile("s_waitcnt vmcnt(4)" ::: "memory");
            else              asm volatile("s_waitcnt vmcnt(6)" ::: "memory");
        } else if (t + 2 == NSTEP) {
            if (NA + NB == 2) asm volatile("s_waitcnt vmcnt(2)" ::: "memory");
            else              asm volatile("s_waitcnt vmcnt(3)" ::: "memory");
        } else {
            asm volatile("s_waitcnt vmcnt(0)" ::: "memory");
        }
        // barrier 2: tile t visible block-wide
        __builtin_amdgcn_s_barrier();
        asm volatile("" ::: "memory");

        const int cb = b0 * BUFB;
        short8 af[MI], bfr[BSL];
#pragma unroll
        for (int i = 0; i < MI; i++)
            af[i] = *(const short8*)(&smem[cb + aoff[i]]);
#pragma unroll
        for (int j = 0; j < BSL; j++)
            bfr[j] = *(const short8*)(&smem[cb + boff[j]]);
#pragma unroll
        for (int i = 0; i < MI; i++)
#pragma unroll
            for (int j = 0; j < BSL; j++)
                acc[i][j] = MFMA32(af[i], bfr[j], acc[i][j]);

        b0 = (b0 == 2) ? 0 : b0 + 1;
        b2 = (b2 == 2) ? 0 : b2 + 1;
    }

#pragma unroll
    for (int i = 0; i < MI; i++) {
#pragma unroll
        for (int j = 0; j < BSL; j++) {
            int n = bn * BN + wn * (BN / 2) + j * 16 + l15;
#pragma unroll
            for (int r = 0; r < 4; r++) {
                int m = bm * 128 + wm * (MI * 16) + i * 16 + quad * 4 + r;
                float fv = acc[i][j][r];
                if (MODE == 1) {
                    outf[(size_t)m * N + n] = fv;
                } else {
                    int t = n >> 10;            // 0=q 1=k 2=v
                    int h = (n >> 6) & 15;
                    int d = n & 63;
                    int b = m >> 11, si = m & 2047;
                    if (t == 2) {
                        // V^T with key interleave within 32-groups
                        int sip = (si & ~31) | (((si >> 2) & 3) << 3)
                                | (((si >> 4) & 1) << 2) | (si & 3);
                        out2[(((size_t)(b * 16 + h)) * 64 + d) * 2048 + sip] = f2bf(fv);
                    } else {
                        // q pre-scaled by 0.125*log2(e) (softmax fold)
                        if (t == 0) fv *= 0.18033688f;
                        size_t off = (((size_t)(b * 16 + h)) * 2048 + si) * 64 + d;
                        unsigned short* dst = (t == 0) ? out0 : out1;
                        dst[off] = f2bf(fv);
                    }
                }
            }
        }
    }
}

// ---------------------------------------------------------------------------
// Flash attention v16 — 8-wave blocks: the round-13 gemm lesson (double
// waves/SIMD at constant work) applied to attn.
// v15 was grid-limited at 2 blk/CU x 4 waves = 2 waves/SIMD. v16 keeps the
// SAME grid (512), SAME 128 q-rows/block, SAME LDS (2 x 16KB), SAME
// KVBLK=64 schedule — but splits the block into 8 waves x 16 q-rows
// (512 threads): 16 waves/CU = 4 waves/SIMD, 2x v15's TLP. Per-wave slice
// halves (1 sub: 18 MFMA/iter, ~30 acc VGPRs; v14's 2-sub variant measured
// 72 VGPR so this fits the (512,4) cap of 128 with margin — no spills).
// Staging re-divides 8 ways: 1 K + 1 V DMA per wave per stage.
// vmcnt ledger/wave: stage(i)[2] + mf[4] + stage(i+1)[2] -> vmcnt(2)
// retires stage(i)+mf(i), keeps stage(i+1); tail vmcnt(0).
// All verified pieces carried: conflict-free 128B-row XOR layouts for K
// and V, q-split wave-complete softmax, full-K=32 PV via key-interleaved
// V^T, mask addend in QK C-init, Q pre-scaled by 0.125*log2e -> exp2 raw,
// T5 setprio around MFMA clusters.
// ---------------------------------------------------------------------------
__global__ __launch_bounds__(512, 4)
void attn_kernel(const unsigned short* __restrict__ Qb,
                 const unsigned short* __restrict__ Kb,
                 const unsigned short* __restrict__ VbT,
                 const float* __restrict__ m2b,
                 const float* __restrict__ gateb,
                 unsigned short* __restrict__ ctx)
{
    __shared__ unsigned char smem[32768];        // 2 x (K 8KB + V 8KB)
    const int S = 2048;
    const int tid  = threadIdx.x;
    const int wave = tid >> 6, lane = tid & 63;  // wave in [0,8)
    const int l15  = lane & 15, quad = lane >> 4;

    int Lid = blockIdx.y * gridDim.x + blockIdx.x;
    int bh = (Lid & 7) * 4 + ((Lid >> 3) & 3);   // [0,32)
    int qc = Lid >> 5;                           // [0,16): 128 q-rows/block
    const int b = bh >> 4, h = bh & 15;
    const int q0 = qc * 128 + wave * 16;         // this wave's 16 q-rows

    const size_t headoff = (size_t)bh * S * 64;
    const unsigned short* Qh  = Qb  + headoff;   // [S][64] (pre-scaled)
    const unsigned short* Kh  = Kb  + headoff;   // [S][64]
    const unsigned short* VhT = VbT + headoff;   // [64][S'] key-interleaved
    const float* m2p = m2b + (size_t)b * S;

    // staging maps (s = wave*64 + lane covers 512 16B-chunks of each 8KB
    // section): line L = s>>3 (K: key row / V: d row, both 128B),
    // slot p = s&7, content chunk c = p^(L&7).
    // K src: (kb+L)*64 + c*8 ; V src: L*2048 + kb + c*8.
    int koff, voff;
    {
        int s = wave * 64 + lane;
        int L = s >> 3, c = (s & 7) ^ (L & 7);
        koff = L * 64 + c * 8;
        voff = L * 2048 + c * 8;
    }
    // read map (shared by K and V: 128B rows, row-XOR slots — verified
    // 0-conflict): row r=l15 within a 16-row subtile, col-chunk j:
    // qkoff[j] = l15*128 + ((j*4+quad) ^ (l15&7))*16 ; add kt*2048 (K) or
    // 8192 + dt*2048 (V).
    int qkoff[2];
#pragma unroll
    for (int j = 0; j < 2; j++)
        qkoff[j] = l15 * 128 + (((j * 4 + quad) ^ (l15 & 7)) * 16);

    // Q B-frags: aq[s2] = Q[q0+l15][s2*32+quad*8+..]
    short8 aq[2];
#pragma unroll
    for (int s2 = 0; s2 < 2; s2++)
        aq[s2] = *(const short8*)(Qh + (size_t)(q0 + l15) * 64 + s2 * 32 + quad * 8);

    floatx4 o[4];                    // O^T partial [dt]
    floatx4 lq = floatx4{0.f, 0.f, 0.f, 0.f};
#pragma unroll
    for (int dt = 0; dt < 4; dt++) o[dt] = floatx4{0.f, 0.f, 0.f, 0.f};

    const uint4v onesu = {0x3F803F80u, 0x3F803F80u, 0x3F803F80u, 0x3F803F80u};
    const short8 ONES = __builtin_bit_cast(short8, onesu);

    // prologue: stage chunk 0 (keys 0..63) into buffer 0
    gl2lds16(Kh + koff, &smem[wave * 1024]);
    gl2lds16(VhT + voff, &smem[8192 + wave * 1024]);

    for (int i = 0; i < 32; i++) {
        const int cb = (i & 1) * 16384;
        const int nb = ((i + 1) & 1) * 16384;
        const int kb = i * 64;
        // mask addends for the 4 key sub-tiles (QK C-init: row == quad*4+r)
        floatx4 mf[4];
#pragma unroll
        for (int t = 0; t < 4; t++)
            mf[t] = *(const floatx4*)(m2p + kb + t * 16 + quad * 4);
        asm volatile("" ::: "memory");
        // barrier 1: all waves done reading buf[nb] (iter i-1)
        __builtin_amdgcn_s_barrier();
        asm volatile("" ::: "memory");
        if (i + 1 < 32) {
            const int kbn = (i + 1) * 64;
            gl2lds16(Kh + (size_t)kbn * 64 + koff, &smem[nb + wave * 1024]);
            gl2lds16(VhT + kbn + voff, &smem[nb + 8192 + wave * 1024]);
            // retire stage(i)+mf(i); stage(i+1)'s 2 stay in flight
            asm volatile("s_waitcnt vmcnt(2)" ::: "memory");
        } else {
            asm volatile("s_waitcnt vmcnt(0)" ::: "memory");
        }
        // barrier 2: whole chunk i visible block-wide
        __builtin_amdgcn_s_barrier();
        asm volatile("" ::: "memory");

        // K frags (consumed by QK before vf loads -> bounded reg pressure)
        short8 kf[4][2];
#pragma unroll
        for (int kt = 0; kt < 4; kt++)
#pragma unroll
            for (int s2 = 0; s2 < 2; s2++)
                kf[kt][s2] = *(const short8*)(&smem[cb + kt * 2048 + qkoff[s2]]);

        // QK: st[kt], C init = mask addend
        floatx4 st[4];
        __builtin_amdgcn_s_setprio(1);
#pragma unroll
        for (int kt = 0; kt < 4; kt++) {
            st[kt] = MFMA32(kf[kt][0], aq[0], mf[kt]);
            st[kt] = MFMA32(kf[kt][1], aq[1], st[kt]);
        }
        __builtin_amdgcn_s_setprio(0);

        // V frags (128B-row swizzle, interleaved key positions)
        short8 vf[4][2];
#pragma unroll
        for (int dt = 0; dt < 4; dt++)
#pragma unroll
            for (int g = 0; g < 2; g++)
                vf[dt][g] = *(const short8*)(&smem[cb + 8192 + dt * 2048 + qkoff[g]]);

        // exp + pack (Q pre-scaled, mask in C-init): pf[g] covers the
        // 32-key group g in interleave order {t0 e0..e3, t1 e0..e3}
        short8 pf[2];
#pragma unroll
        for (int g = 0; g < 2; g++) {
            floatx4 a = st[2 * g], c = st[2 * g + 1];
            uint4v pu = {pack_bf2(EXP2(a[0]), EXP2(a[1])),
                         pack_bf2(EXP2(a[2]), EXP2(a[3])),
                         pack_bf2(EXP2(c[0]), EXP2(c[1])),
                         pack_bf2(EXP2(c[2]), EXP2(c[3]))};
            pf[g] = __builtin_bit_cast(short8, pu);
        }

        // PV + l: full-K=32 per group, un-padded
        __builtin_amdgcn_s_setprio(1);
#pragma unroll
        for (int g = 0; g < 2; g++) {
#pragma unroll
            for (int dt = 0; dt < 4; dt++)
                o[dt] = MFMA32(vf[dt][g], pf[g], o[dt]);
            lq = MFMA32(ONES, pf[g], lq);
        }
        __builtin_amdgcn_s_setprio(0);
    }

    // epilogue: wave-complete softmax; lane writes q = q0 + l15, all dt
    float iv = gateb[h] / lq[0];
    size_t base = ((size_t)(b * 2048 + q0 + l15)) * 1024 + h * 64 + quad * 4;
#pragma unroll
    for (int dt = 0; dt < 4; dt++) {
        uint2v w;
        w[0] = pack_bf2(o[dt][0] * iv, o[dt][1] * iv);
        w[1] = pack_bf2(o[dt][2] * iv, o[dt][3] * iv);
        *(uint2v*)(ctx + base + dt * 16) = w;
    }
}

// ---------------------------------------------------------------------------
extern "C" void kernel_launch(void* const* d_in, const int* in_sizes, int n_in,
                              void* d_out, int out_size, void* d_ws, size_t ws_size,
                              hipStream_t stream)
{
    const float* hidden = (const float*)d_in[0]; // [2,2048,1024] fp32
    const float* mask   = (const float*)d_in[1]; // [2,1,1,2048]  fp32
    const float* w_qkv  = (const float*)d_in[2]; // [3072,1024]   fp32
    const float* w_out  = (const float*)d_in[3]; // [1024,1024]   fp32
    const float* gate   = (const float*)d_in[4]; // [16]          fp32
    float* out = (float*)d_out;                  // [2,2048,1024] fp32

    unsigned short* q_buf = (unsigned short*)d_ws;   // [2,16,2048,64] bf16 (pre-scaled)
    unsigned short* k_buf = q_buf + 4194304;         // [2,16,2048,64]
    unsigned short* v_buf = k_buf + 4194304;         // [2,16,64,2048] (V^T, interleaved)
    unsigned short* c_buf = v_buf + 4194304;         // [2,2048,1024]  bf16
    unsigned short* h_bf  = c_buf + 4194304;         // hidden bf16
    unsigned short* wq_bf = h_bf  + 4194304;         // w_qkv bf16
    unsigned short* wo_bf = wq_bf + 3145728;         // w_out bf16
    float* m2_buf = (float*)(wo_bf + 1048576);       // [2,2048] fp32

    // one-pass prep: fp32->bf16 converts + mask transform
    cvt_all<<<8196, 256, 0, stream>>>(hidden, w_qkv, w_out, mask,
                                      h_bf, wq_bf, wo_bf, m2_buf);

    // QKV projection, scatter q(pre-scaled)/k/V^T(interleaved) — 8-wave blocks
    gemm_nt<0, 128, 8><<<dim3(24, 32), 512, 0, stream>>>(h_bf, wq_bf, q_buf, k_buf, v_buf, nullptr, 3072);
    // fused flash attention + gate -> ctx bf16 (128-q blocks of 8 waves, grid 512)
    attn_kernel<<<dim3(16, 32), 512, 0, stream>>>(q_buf, k_buf, v_buf, m2_buf, gate, c_buf);
    // output projection -> out fp32 (grid 16x32, 128x64 tiles) — 4-wave blocks
    gemm_nt<1, 64, 4><<<dim3(16, 32), 256, 0, stream>>>(c_buf, wo_bf, nullptr, nullptr, nullptr, out, 1024);
}